// Round 1
// baseline (2361.478 us; speedup 1.0000x reference)
//
#include <hip/hip_runtime.h>

#define NN 50000     // nodes
#define NE 600000    // directed edges (self loops handled separately)
#define NG 64        // graphs
#define DIM 128      // feature dim (D == H == 128)
#define NCLS 10

// ---------------- degree / norm ----------------
__global__ void k_deg_init(float* deg) {
    int i = blockIdx.x * blockDim.x + threadIdx.x;
    if (i < NN) deg[i] = 1.0f;              // self loop contributes 1
}

__global__ void k_deg_count(const int* __restrict__ col, float* deg) {
    int e = blockIdx.x * blockDim.x + threadIdx.x;
    if (e < NE) atomicAdd(&deg[col[e]], 1.0f);
}

__global__ void k_dinv(float* deg) {
    int i = blockIdx.x * blockDim.x + threadIdx.x;
    if (i < NN) deg[i] = rsqrtf(deg[i]);
}

// ---------------- GEMM: C[n,c] = sum_k f(A[n,k]) * W[k,c] ----------------
// f(x) = relu(x + bias[k]) when RELU, else identity. 32 rows per block.
template <bool RELU>
__global__ __launch_bounds__(256) void k_gemm(const float* __restrict__ A,
                                              const float* __restrict__ W,
                                              const float* __restrict__ bias,
                                              float* __restrict__ C) {
    __shared__ float Ws[DIM][DIM];   // 64 KB
    __shared__ float Xs[32][DIM];    // 16 KB
    const int t = threadIdx.x;

    // stage W: 16384 floats = 4096 float4 / 256 threads = 16 each (coalesced)
    const float4* W4 = (const float4*)W;
    float4* Ws4 = (float4*)&Ws[0][0];
#pragma unroll
    for (int j = 0; j < 16; ++j) Ws4[t + j * 256] = W4[t + j * 256];

    // stage X tile: 32 rows x 128 = 1024 float4 / 256 threads = 4 each
    const int row0 = blockIdx.x * 32;
    const float4* A4 = (const float4*)A;
    float4* Xs4 = (float4*)&Xs[0][0];
#pragma unroll
    for (int j = 0; j < 4; ++j) {
        int idx = t + j * 256;       // float4 index in tile
        int r = idx >> 5;            // 32 float4 per row
        int k4 = idx & 31;
        int node = row0 + r;
        float4 v = make_float4(0.f, 0.f, 0.f, 0.f);
        if (node < NN) v = A4[(size_t)node * 32 + k4];
        if (RELU) {
            float4 b = ((const float4*)bias)[k4];
            v.x = fmaxf(v.x + b.x, 0.f);
            v.y = fmaxf(v.y + b.y, 0.f);
            v.z = fmaxf(v.z + b.z, 0.f);
            v.w = fmaxf(v.w + b.w, 0.f);
        }
        Xs4[idx] = v;
    }
    __syncthreads();

    const int c = t & 127;           // output column
    const int sub = t >> 7;          // 0/1 -> rows 0..15 / 16..31
    const int rbase = sub * 16;

    float acc[16];
#pragma unroll
    for (int i = 0; i < 16; ++i) acc[i] = 0.f;

    for (int k = 0; k < DIM; k += 4) {
        float w0 = Ws[k + 0][c];
        float w1 = Ws[k + 1][c];
        float w2 = Ws[k + 2][c];
        float w3 = Ws[k + 3][c];
#pragma unroll
        for (int i = 0; i < 16; ++i) {
            float4 xv = *(const float4*)&Xs[rbase + i][k];   // wave-broadcast
            acc[i] += xv.x * w0 + xv.y * w1 + xv.z * w2 + xv.w * w3;
        }
    }

#pragma unroll
    for (int i = 0; i < 16; ++i) {
        int node = row0 + rbase + i;
        if (node < NN) C[(size_t)node * DIM + c] = acc[i];
    }
}

// ---------------- aggregation buffer init with fused self-loop ----------------
// out[i,:] = dinv[i]^2 * H[i,:]
__global__ void k_selfloop_init(const float* __restrict__ H,
                                const float* __restrict__ dinv,
                                float* __restrict__ out) {
    int gt = blockIdx.x * blockDim.x + threadIdx.x;
    int i = gt >> 5, lane = gt & 31;
    if (i >= NN) return;
    float d = dinv[i];
    float s = d * d;
    float4 v = ((const float4*)(H + (size_t)i * DIM))[lane];
    v.x *= s; v.y *= s; v.z *= s; v.w *= s;
    ((float4*)(out + (size_t)i * DIM))[lane] = v;
}

// ---------------- edge scatter: out[col] += dinv[row]*dinv[col] * H[row] ----
__global__ void k_scatter(const int* __restrict__ row,
                          const int* __restrict__ col,
                          const float* __restrict__ dinv,
                          const float* __restrict__ H,
                          float* __restrict__ out) {
    int gt = blockIdx.x * blockDim.x + threadIdx.x;
    int e = gt >> 5, lane = gt & 31;
    if (e >= NE) return;
    int r = row[e], c = col[e];
    float nrm = dinv[r] * dinv[c];
    float4 v = ((const float4*)(H + (size_t)r * DIM))[lane];
    float* o = out + (size_t)c * DIM + lane * 4;
    atomicAdd(o + 0, nrm * v.x);
    atomicAdd(o + 1, nrm * v.y);
    atomicAdd(o + 2, nrm * v.z);
    atomicAdd(o + 3, nrm * v.w);
}

// ---------------- pool (mean over sorted batch) + linear head ----------------
__global__ __launch_bounds__(256) void k_pool_logits(const float* __restrict__ Hf,
                                                     const float* __restrict__ b2,
                                                     const float* __restrict__ Wlin,
                                                     const float* __restrict__ blin,
                                                     const int* __restrict__ batch,
                                                     float* __restrict__ out) {
    const int g = blockIdx.x;
    const int t = threadIdx.x;
    // lower_bound(batch, g) and lower_bound(batch, g+1); batch is sorted
    int start;
    { int a = 0, b = NN; while (a < b) { int m = (a + b) >> 1; if (batch[m] < g) a = m + 1; else b = m; } start = a; }
    int end;
    { int a = 0, b = NN; while (a < b) { int m = (a + b) >> 1; if (batch[m] < g + 1) a = m + 1; else b = m; } end = a; }
    const int cnt = end - start;

    const int c = t & 127, half = t >> 7;
    float acc = 0.f;
    for (int i = start + half; i < end; i += 2)
        acc += Hf[(size_t)i * DIM + c];

    __shared__ float sm[2][DIM];
    __shared__ float pooled[DIM];
    sm[half][c] = acc;
    __syncthreads();
    if (t < DIM) {
        float s = sm[0][t] + sm[1][t];
        pooled[t] = (cnt > 0) ? (s / (float)cnt + b2[t]) : 0.f;
    }
    __syncthreads();
    if (t < NCLS) {
        float s = blin[t];
        for (int k = 0; k < DIM; ++k) s += pooled[k] * Wlin[k * NCLS + t];
        out[g * NCLS + t] = s;
    }
}

extern "C" void kernel_launch(void* const* d_in, const int* in_sizes, int n_in,
                              void* d_out, int out_size, void* d_ws, size_t ws_size,
                              hipStream_t stream) {
    const float* x    = (const float*)d_in[0];
    const float* W1   = (const float*)d_in[1];
    const float* b1   = (const float*)d_in[2];
    const float* W2   = (const float*)d_in[3];
    const float* b2   = (const float*)d_in[4];
    const float* Wlin = (const float*)d_in[5];
    const float* blin = (const float*)d_in[6];
    const int* eidx   = (const int*)d_in[7];   // [2, E] flat: rows then cols
    const int* batch  = (const int*)d_in[8];
    float* out = (float*)d_out;

    char* ws = (char*)d_ws;
    float* dinv = (float*)ws;                              // N floats (200000 B, 16B-aligned)
    float* bufA = (float*)(ws + (size_t)NN * 4);           // N*DIM floats
    float* bufB = bufA + (size_t)NN * DIM;                 // N*DIM floats

    const int* erow = eidx;
    const int* ecol = eidx + NE;

    // degrees -> dinv
    k_deg_init<<<(NN + 255) / 256, 256, 0, stream>>>(dinv);
    k_deg_count<<<(NE + 255) / 256, 256, 0, stream>>>(ecol, dinv);
    k_dinv<<<(NN + 255) / 256, 256, 0, stream>>>(dinv);

    const int gemm_grid = (NN + 31) / 32;
    const int edge_grid = (NE * 32) / 256;     // 75000
    const int node_grid = (NN * 32) / 256;     // 6250

    // layer 1: h0 = x @ W1 ; agg1 = Ahat * h0
    k_gemm<false><<<gemm_grid, 256, 0, stream>>>(x, W1, nullptr, bufA);
    k_selfloop_init<<<node_grid, 256, 0, stream>>>(bufA, dinv, bufB);
    k_scatter<<<edge_grid, 256, 0, stream>>>(erow, ecol, dinv, bufA, bufB);

    // layer 2: h1g = relu(agg1 + b1) @ W2 ; agg2 = Ahat * h1g
    k_gemm<true><<<gemm_grid, 256, 0, stream>>>(bufB, W2, b1, bufA);
    k_selfloop_init<<<node_grid, 256, 0, stream>>>(bufA, dinv, bufB);
    k_scatter<<<edge_grid, 256, 0, stream>>>(erow, ecol, dinv, bufA, bufB);

    // pool (+b2) + linear head
    k_pool_logits<<<NG, 256, 0, stream>>>(bufB, b2, Wlin, blin, batch, out);
}

// Round 2
// 605.226 us; speedup vs baseline: 3.9018x; 3.9018x over previous
//
#include <hip/hip_runtime.h>

#define NN 50000     // nodes
#define NE 600000    // directed edges (self loops handled separately)
#define NG 64        // graphs
#define DIM 128      // feature dim (D == H == 128)
#define NCLS 10

// ---------------- degree histogram (int) ----------------
__global__ void k_deg_count(const int* __restrict__ col, int* __restrict__ cnt) {
    int e = blockIdx.x * blockDim.x + threadIdx.x;
    if (e < NE) atomicAdd(&cnt[col[e]], 1);
}

// dinv[i] = rsqrt(1 + indeg[i])   (self loop contributes 1)
__global__ void k_dinv(const int* __restrict__ cnt, float* __restrict__ dinv) {
    int i = blockIdx.x * blockDim.x + threadIdx.x;
    if (i < NN) dinv[i] = rsqrtf(1.0f + (float)cnt[i]);
}

// ---------------- exclusive scan over cnt -> offsets, cursor ----------------
__global__ __launch_bounds__(256) void k_scan(const int* __restrict__ cnt,
                                              int* __restrict__ offsets,
                                              int* __restrict__ cursor) {
    __shared__ int sums[256];
    const int t = threadIdx.x;
    const int CH = (NN + 255) / 256;            // 196
    const int begin = t * CH;
    const int end = min(begin + CH, NN);
    int s = 0;
    for (int i = begin; i < end; ++i) s += cnt[i];
    sums[t] = s;
    __syncthreads();
    for (int off = 1; off < 256; off <<= 1) {
        int v = (t >= off) ? sums[t - off] : 0;
        __syncthreads();
        sums[t] += v;
        __syncthreads();
    }
    int run = (t > 0) ? sums[t - 1] : 0;
    for (int i = begin; i < end; ++i) {
        offsets[i] = run;
        cursor[i] = run;
        run += cnt[i];
    }
    if (t == 255) offsets[NN] = run;
}

// ---------------- CSR fill: csr_src sorted by destination ----------------
__global__ void k_csr_fill(const int* __restrict__ row, const int* __restrict__ col,
                           int* __restrict__ cursor, int* __restrict__ csr) {
    int e = blockIdx.x * blockDim.x + threadIdx.x;
    if (e < NE) {
        int c = col[e];
        int p = atomicAdd(&cursor[c], 1);
        csr[p] = row[e];
    }
}

// ---------------- GEMM: C[n,c] = dinv[n] * sum_k f(A[n,k]) * W[k,c] --------
// f(x) = relu(x + bias[k]) when RELU, else identity. 32 rows per block.
template <bool RELU>
__global__ __launch_bounds__(256) void k_gemm(const float* __restrict__ A,
                                              const float* __restrict__ W,
                                              const float* __restrict__ bias,
                                              const float* __restrict__ dinv,
                                              float* __restrict__ C) {
    __shared__ float Ws[DIM][DIM];   // 64 KB
    __shared__ float Xs[32][DIM];    // 16 KB
    const int t = threadIdx.x;

    // stage W: 16384 floats = 4096 float4 / 256 threads = 16 each (coalesced)
    const float4* W4 = (const float4*)W;
    float4* Ws4 = (float4*)&Ws[0][0];
#pragma unroll
    for (int j = 0; j < 16; ++j) Ws4[t + j * 256] = W4[t + j * 256];

    // stage X tile: 32 rows x 128 = 1024 float4 / 256 threads = 4 each
    const int row0 = blockIdx.x * 32;
    const float4* A4 = (const float4*)A;
    float4* Xs4 = (float4*)&Xs[0][0];
#pragma unroll
    for (int j = 0; j < 4; ++j) {
        int idx = t + j * 256;       // float4 index in tile
        int r = idx >> 5;            // 32 float4 per row
        int k4 = idx & 31;
        int node = row0 + r;
        float4 v = make_float4(0.f, 0.f, 0.f, 0.f);
        if (node < NN) v = A4[(size_t)node * 32 + k4];
        if (RELU) {
            float4 b = ((const float4*)bias)[k4];
            v.x = fmaxf(v.x + b.x, 0.f);
            v.y = fmaxf(v.y + b.y, 0.f);
            v.z = fmaxf(v.z + b.z, 0.f);
            v.w = fmaxf(v.w + b.w, 0.f);
        }
        Xs4[idx] = v;
    }
    __syncthreads();

    const int c = t & 127;           // output column
    const int sub = t >> 7;          // 0/1 -> rows 0..15 / 16..31
    const int rbase = sub * 16;

    float acc[16];
#pragma unroll
    for (int i = 0; i < 16; ++i) acc[i] = 0.f;

    for (int k = 0; k < DIM; k += 4) {
        float w0 = Ws[k + 0][c];
        float w1 = Ws[k + 1][c];
        float w2 = Ws[k + 2][c];
        float w3 = Ws[k + 3][c];
#pragma unroll
        for (int i = 0; i < 16; ++i) {
            float4 xv = *(const float4*)&Xs[rbase + i][k];   // wave-broadcast
            acc[i] += xv.x * w0 + xv.y * w1 + xv.z * w2 + xv.w * w3;
        }
    }

#pragma unroll
    for (int i = 0; i < 16; ++i) {
        int node = row0 + rbase + i;
        if (node < NN) C[(size_t)node * DIM + c] = dinv[node] * acc[i];
    }
}

// ---------------- CSR gather: out[c] = dinv[c] * (Hs[c] + sum_{r->c} Hs[r]) -
// Hs is already row-scaled by dinv (GEMM epilogue). 32 lanes per node.
__global__ __launch_bounds__(256) void k_gather(const int* __restrict__ offsets,
                                                const int* __restrict__ csr,
                                                const float* __restrict__ dinv,
                                                const float* __restrict__ Hs,
                                                float* __restrict__ out) {
    int gt = blockIdx.x * blockDim.x + threadIdx.x;
    int node = gt >> 5, lane = gt & 31;
    if (node >= NN) return;
    int beg = offsets[node], end = offsets[node + 1];
    // self loop term: Hs[node] (already carries dinv[node])
    float4 acc = ((const float4*)(Hs + (size_t)node * DIM))[lane];
    for (int e = beg; e < end; ++e) {
        int r = csr[e];
        float4 v = ((const float4*)(Hs + (size_t)r * DIM))[lane];
        acc.x += v.x; acc.y += v.y; acc.z += v.z; acc.w += v.w;
    }
    float d = dinv[node];
    acc.x *= d; acc.y *= d; acc.z *= d; acc.w *= d;
    ((float4*)(out + (size_t)node * DIM))[lane] = acc;
}

// ---------------- pool (mean over sorted batch) + linear head ----------------
__global__ __launch_bounds__(256) void k_pool_logits(const float* __restrict__ Hf,
                                                     const float* __restrict__ b2,
                                                     const float* __restrict__ Wlin,
                                                     const float* __restrict__ blin,
                                                     const int* __restrict__ batch,
                                                     float* __restrict__ out) {
    const int g = blockIdx.x;
    const int t = threadIdx.x;
    int start;
    { int a = 0, b = NN; while (a < b) { int m = (a + b) >> 1; if (batch[m] < g) a = m + 1; else b = m; } start = a; }
    int end;
    { int a = 0, b = NN; while (a < b) { int m = (a + b) >> 1; if (batch[m] < g + 1) a = m + 1; else b = m; } end = a; }
    const int cnt = end - start;

    const int c = t & 127, half = t >> 7;
    float acc = 0.f;
    for (int i = start + half; i < end; i += 2)
        acc += Hf[(size_t)i * DIM + c];

    __shared__ float sm[2][DIM];
    __shared__ float pooled[DIM];
    sm[half][c] = acc;
    __syncthreads();
    if (t < DIM) {
        float s = sm[0][t] + sm[1][t];
        pooled[t] = (cnt > 0) ? (s / (float)cnt + b2[t]) : 0.f;
    }
    __syncthreads();
    if (t < NCLS) {
        float s = blin[t];
        for (int k = 0; k < DIM; ++k) s += pooled[k] * Wlin[k * NCLS + t];
        out[g * NCLS + t] = s;
    }
}

extern "C" void kernel_launch(void* const* d_in, const int* in_sizes, int n_in,
                              void* d_out, int out_size, void* d_ws, size_t ws_size,
                              hipStream_t stream) {
    const float* x    = (const float*)d_in[0];
    const float* W1   = (const float*)d_in[1];
    const float* b1   = (const float*)d_in[2];
    const float* W2   = (const float*)d_in[3];
    const float* b2   = (const float*)d_in[4];
    const float* Wlin = (const float*)d_in[5];
    const float* blin = (const float*)d_in[6];
    const int* eidx   = (const int*)d_in[7];   // [2, E] flat: rows then cols
    const int* batch  = (const int*)d_in[8];
    float* out = (float*)d_out;

    char* ws = (char*)d_ws;
    float* dinv   = (float*)ws;                               // NN floats
    int*   cnt    = (int*)(ws + (size_t)NN * 4);              // NN ints (becomes cursor)
    int*   offs   = (int*)(ws + (size_t)NN * 8);              // NN+1 ints
    int*   csr    = (int*)(ws + (size_t)NN * 12 + 16);        // NE ints
    float* bufA   = (float*)(ws + (size_t)NN * 12 + 16 + (size_t)NE * 4);
    float* bufB   = bufA + (size_t)NN * DIM;

    const int* erow = eidx;
    const int* ecol = eidx + NE;

    // ---- CSR build + norms ----
    hipMemsetAsync(cnt, 0, (size_t)NN * 4, stream);
    k_deg_count<<<(NE + 255) / 256, 256, 0, stream>>>(ecol, cnt);
    k_dinv<<<(NN + 255) / 256, 256, 0, stream>>>(cnt, dinv);
    k_scan<<<1, 256, 0, stream>>>(cnt, offs, cnt /*cursor overwrites cnt*/);
    k_csr_fill<<<(NE + 255) / 256, 256, 0, stream>>>(erow, ecol, cnt, csr);

    const int gemm_grid = (NN + 31) / 32;
    const int node_grid = (NN * 32 + 255) / 256;   // 6250

    // layer 1: Hs = dinv * (x @ W1) ; agg1 = dinv * (self + neighbors)
    k_gemm<false><<<gemm_grid, 256, 0, stream>>>(x, W1, nullptr, dinv, bufA);
    k_gather<<<node_grid, 256, 0, stream>>>(offs, csr, dinv, bufA, bufB);

    // layer 2: Hs2 = dinv * (relu(agg1 + b1) @ W2) ; agg2 likewise
    k_gemm<true><<<gemm_grid, 256, 0, stream>>>(bufB, W2, b1, dinv, bufA);
    k_gather<<<node_grid, 256, 0, stream>>>(offs, csr, dinv, bufA, bufB);

    // pool (+b2) + linear head
    k_pool_logits<<<NG, 256, 0, stream>>>(bufB, b2, Wlin, blin, batch, out);
}

// Round 3
// 379.146 us; speedup vs baseline: 6.2284x; 1.5963x over previous
//
#include <hip/hip_runtime.h>

#define NN 50000     // nodes
#define NE 600000    // directed edges (self loops handled separately)
#define NG 64        // graphs
#define DIM 128      // feature dim (D == H == 128)
#define NCLS 10

typedef unsigned short ushort;
typedef __attribute__((ext_vector_type(8))) short short8;   // 8 bf16 (4 VGPRs)
typedef __attribute__((ext_vector_type(4))) float float4v;  // 4 fp32 acc

__device__ __forceinline__ ushort f2bf(float f) {
    unsigned u = __float_as_uint(f);
    u += 0x7fff + ((u >> 16) & 1);          // RNE
    return (ushort)(u >> 16);
}
__device__ __forceinline__ float bf2f(ushort h) {
    return __uint_as_float((unsigned)h << 16);
}

// ---------------- degree histogram (int) ----------------
__global__ void k_deg_count(const int* __restrict__ col, int* __restrict__ cnt) {
    int e = blockIdx.x * blockDim.x + threadIdx.x;
    if (e < NE) atomicAdd(&cnt[col[e]], 1);
}

// dinv[i] = rsqrt(1 + indeg[i])   (self loop contributes 1)
__global__ void k_dinv(const int* __restrict__ cnt, float* __restrict__ dinv) {
    int i = blockIdx.x * blockDim.x + threadIdx.x;
    if (i < NN) dinv[i] = rsqrtf(1.0f + (float)cnt[i]);
}

// ---------------- parallel scan: 196-block partial sums ----------------
__global__ __launch_bounds__(256) void k_part(const int* __restrict__ cnt,
                                              int* __restrict__ partials) {
    __shared__ int sm[256];
    int t = threadIdx.x, i = blockIdx.x * 256 + t;
    sm[t] = (i < NN) ? cnt[i] : 0;
    __syncthreads();
    for (int s = 128; s > 0; s >>= 1) {
        if (t < s) sm[t] += sm[t + s];
        __syncthreads();
    }
    if (t == 0) partials[blockIdx.x] = sm[0];
}

// 1-block exclusive scan of the 196 partials
__global__ __launch_bounds__(256) void k_scanp(int* partials) {
    __shared__ int sm[256];
    int t = threadIdx.x;
    int v = (t < 196) ? partials[t] : 0;
    sm[t] = v;
    __syncthreads();
    for (int off = 1; off < 256; off <<= 1) {
        int u = (t >= off) ? sm[t - off] : 0;
        __syncthreads();
        sm[t] += u;
        __syncthreads();
    }
    if (t < 196) partials[t] = sm[t] - v;   // exclusive prefix
}

// per-block exclusive scan + base -> offsets & cursor (cursor may alias cnt_in)
__global__ __launch_bounds__(256) void k_off(const int* cnt_in, const int* __restrict__ partials,
                                             int* __restrict__ offsets, int* cursor) {
    __shared__ int sm[256];
    int t = threadIdx.x, i = blockIdx.x * 256 + t;
    int v = (i < NN) ? cnt_in[i] : 0;
    sm[t] = v;
    __syncthreads();
    for (int off = 1; off < 256; off <<= 1) {
        int u = (t >= off) ? sm[t - off] : 0;
        __syncthreads();
        sm[t] += u;
        __syncthreads();
    }
    int base = partials[blockIdx.x] + sm[t] - v;
    if (i < NN) { offsets[i] = base; cursor[i] = base; }
    if (i == NN) offsets[NN] = base;        // v==0 there => total edge count
}

// ---------------- CSR fill: sources sorted by destination ----------------
__global__ void k_csr_fill(const int* __restrict__ row, const int* __restrict__ col,
                           int* __restrict__ cursor, int* __restrict__ csr) {
    int e = blockIdx.x * blockDim.x + threadIdx.x;
    if (e < NE) {
        int c = col[e];
        int p = atomicAdd(&cursor[c], 1);
        csr[p] = row[e];
    }
}

// ---------------- W -> bf16 B-fragment order ----------------
// Wsw[(nt*4+kc)*64 + lane][j] = W[kc*32 + (lane>>4)*8 + j][nt*16 + (lane&15)]
__global__ void k_wprep(const float* __restrict__ W1, const float* __restrict__ W2,
                        ushort* __restrict__ Wsw) {
    int tid = blockIdx.x * blockDim.x + threadIdx.x;   // 2*16384 threads
    int layer = tid >> 14;
    int r = tid & 16383;
    int j = r & 7;
    int lane = (r >> 3) & 63;
    int frag = r >> 9;             // nt*4+kc
    int nt = frag >> 2, kc = frag & 3;
    int k = kc * 32 + (lane >> 4) * 8 + j;
    int n = nt * 16 + (lane & 15);
    const float* W = layer ? W2 : W1;
    Wsw[tid] = f2bf(W[k * DIM + n]);
}

// ---------------- MFMA GEMM: Hs[n,c] = dinv[n] * sum_k A[n,k] W[k,c] -------
// 4 waves/block, 16 rows per wave, full 128-col strip. All 32 B-frags in regs.
template <bool IN_BF16>
__global__ __launch_bounds__(256) void k_gemm_mfma(const void* __restrict__ Ain,
                                                   const ushort* __restrict__ Wsw,
                                                   const float* __restrict__ dinv,
                                                   ushort* __restrict__ Hs) {
    const int t = threadIdx.x;
    const int wave = t >> 6, lane = t & 63;
    const int m = lane & 15, quad = lane >> 4;
    const int row0 = blockIdx.x * 64 + wave * 16;

    short8 bfrag[8][4];
#pragma unroll
    for (int nt = 0; nt < 8; ++nt)
#pragma unroll
        for (int kc = 0; kc < 4; ++kc)
            bfrag[nt][kc] = *(const short8*)(Wsw + ((nt * 4 + kc) * 64 + lane) * 8);

    float4v acc[8];
#pragma unroll
    for (int nt = 0; nt < 8; ++nt) acc[nt] = (float4v){0.f, 0.f, 0.f, 0.f};

    const int row = row0 + m;
    const int rclamp = row < NN ? row : NN - 1;

#pragma unroll
    for (int kc = 0; kc < 4; ++kc) {
        short8 a;
        if (IN_BF16) {
            a = *(const short8*)((const ushort*)Ain + (size_t)rclamp * DIM + kc * 32 + quad * 8);
        } else {
            const float* ap = (const float*)Ain + (size_t)rclamp * DIM + kc * 32 + quad * 8;
            float4 v0 = *(const float4*)ap;
            float4 v1 = *(const float4*)(ap + 4);
            union { short8 v; ushort u[8]; } tmp;
            tmp.u[0] = f2bf(v0.x); tmp.u[1] = f2bf(v0.y);
            tmp.u[2] = f2bf(v0.z); tmp.u[3] = f2bf(v0.w);
            tmp.u[4] = f2bf(v1.x); tmp.u[5] = f2bf(v1.y);
            tmp.u[6] = f2bf(v1.z); tmp.u[7] = f2bf(v1.w);
            a = tmp.v;
        }
#pragma unroll
        for (int nt = 0; nt < 8; ++nt)
            acc[nt] = __builtin_amdgcn_mfma_f32_16x16x32_bf16(a, bfrag[nt][kc], acc[nt], 0, 0, 0);
    }

    // C/D: col = nt*16 + (lane&15), row = row0 + quad*4 + reg
#pragma unroll
    for (int reg = 0; reg < 4; ++reg) {
        int r = row0 + quad * 4 + reg;
        if (r < NN) {
            float d = dinv[r];
#pragma unroll
            for (int nt = 0; nt < 8; ++nt)
                Hs[(size_t)r * DIM + nt * 16 + m] = f2bf(d * acc[nt][reg]);
        }
    }
}

// ---------------- CSR gather (bf16): out = dinv[c]*(Hs[c] + sum Hs[r]) -----
// RELU: out = relu(out + b1) (feeds next GEMM). 32 lanes per node, 4 cols/lane.
template <bool RELU>
__global__ __launch_bounds__(256) void k_gather_bf(const int* __restrict__ offsets,
                                                   const int* __restrict__ csr,
                                                   const float* __restrict__ dinv,
                                                   const float* __restrict__ bias,
                                                   const ushort* __restrict__ Hs,
                                                   ushort* __restrict__ out) {
    int gt = blockIdx.x * blockDim.x + threadIdx.x;
    int node = gt >> 5, lane = gt & 31;
    if (node >= NN) return;
    int beg = offsets[node], end = offsets[node + 1];

    uint2 sv = *(const uint2*)(Hs + (size_t)node * DIM + lane * 4);
    float a0 = __uint_as_float(sv.x << 16);
    float a1 = __uint_as_float(sv.x & 0xffff0000u);
    float a2 = __uint_as_float(sv.y << 16);
    float a3 = __uint_as_float(sv.y & 0xffff0000u);

    for (int e = beg; e < end; ++e) {
        int r = csr[e];
        uint2 v = *(const uint2*)(Hs + (size_t)r * DIM + lane * 4);
        a0 += __uint_as_float(v.x << 16);
        a1 += __uint_as_float(v.x & 0xffff0000u);
        a2 += __uint_as_float(v.y << 16);
        a3 += __uint_as_float(v.y & 0xffff0000u);
    }
    float d = dinv[node];
    a0 *= d; a1 *= d; a2 *= d; a3 *= d;
    if (RELU) {
        float4 b = *(const float4*)(bias + lane * 4);
        a0 = fmaxf(a0 + b.x, 0.f);
        a1 = fmaxf(a1 + b.y, 0.f);
        a2 = fmaxf(a2 + b.z, 0.f);
        a3 = fmaxf(a3 + b.w, 0.f);
    }
    uint2 o;
    o.x = (unsigned)f2bf(a0) | ((unsigned)f2bf(a1) << 16);
    o.y = (unsigned)f2bf(a2) | ((unsigned)f2bf(a3) << 16);
    *(uint2*)(out + (size_t)node * DIM + lane * 4) = o;
}

// ---------------- pool (mean over sorted batch) + linear head ----------------
__global__ __launch_bounds__(256) void k_pool_logits(const ushort* __restrict__ Hf,
                                                     const float* __restrict__ b2,
                                                     const float* __restrict__ Wlin,
                                                     const float* __restrict__ blin,
                                                     const int* __restrict__ batch,
                                                     float* __restrict__ out) {
    const int g = blockIdx.x;
    const int t = threadIdx.x;
    int start;
    { int a = 0, b = NN; while (a < b) { int m = (a + b) >> 1; if (batch[m] < g) a = m + 1; else b = m; } start = a; }
    int end;
    { int a = 0, b = NN; while (a < b) { int m = (a + b) >> 1; if (batch[m] < g + 1) a = m + 1; else b = m; } end = a; }
    const int cnt = end - start;

    const int c = t & 127, half = t >> 7;
    float acc = 0.f;
    for (int i = start + half; i < end; i += 2)
        acc += bf2f(Hf[(size_t)i * DIM + c]);

    __shared__ float sm[2][DIM];
    __shared__ float pooled[DIM];
    sm[half][c] = acc;
    __syncthreads();
    if (t < DIM) {
        float s = sm[0][t] + sm[1][t];
        pooled[t] = (cnt > 0) ? (s / (float)cnt + b2[t]) : 0.f;
    }
    __syncthreads();
    if (t < NCLS) {
        float s = blin[t];
        for (int k = 0; k < DIM; ++k) s += pooled[k] * Wlin[k * NCLS + t];
        out[g * NCLS + t] = s;
    }
}

extern "C" void kernel_launch(void* const* d_in, const int* in_sizes, int n_in,
                              void* d_out, int out_size, void* d_ws, size_t ws_size,
                              hipStream_t stream) {
    const float* x    = (const float*)d_in[0];
    const float* W1   = (const float*)d_in[1];
    const float* b1   = (const float*)d_in[2];
    const float* W2   = (const float*)d_in[3];
    const float* b2   = (const float*)d_in[4];
    const float* Wlin = (const float*)d_in[5];
    const float* blin = (const float*)d_in[6];
    const int* eidx   = (const int*)d_in[7];   // [2, E] flat: rows then cols
    const int* batch  = (const int*)d_in[8];
    float* out = (float*)d_out;

    char* ws = (char*)d_ws;
    float*  dinv     = (float*)(ws + 0);                   // 200000 B
    int*    cnt      = (int*)(ws + 200000);                // 200000 B (becomes cursor)
    int*    offs     = (int*)(ws + 400000);                // 200016 B (NN+1)
    int*    csr      = (int*)(ws + 600016);                // 2400000 B
    int*    partials = (int*)(ws + 3000016);               // 1024 B
    ushort* Wsw      = (ushort*)(ws + 3001040);            // 65536 B (2 layers)
    ushort* bufA     = (ushort*)(ws + 3066576);            // 12.8 MB bf16 [NN][128]
    ushort* bufB     = (ushort*)(ws + 3066576 + (size_t)NN * DIM * 2);

    const int* erow = eidx;
    const int* ecol = eidx + NE;

    // ---- CSR build + norms ----
    hipMemsetAsync(cnt, 0, (size_t)NN * 4, stream);
    k_deg_count<<<(NE + 255) / 256, 256, 0, stream>>>(ecol, cnt);
    k_dinv<<<(NN + 255) / 256, 256, 0, stream>>>(cnt, dinv);
    const int SB = (NN + 255) / 256;   // 196
    k_part<<<SB, 256, 0, stream>>>(cnt, partials);
    k_scanp<<<1, 256, 0, stream>>>(partials);
    k_off<<<SB, 256, 0, stream>>>(cnt, partials, offs, cnt /*cursor*/);
    k_csr_fill<<<(NE + 255) / 256, 256, 0, stream>>>(erow, ecol, cnt, csr);

    // ---- weights -> bf16 fragment order ----
    k_wprep<<<128, 256, 0, stream>>>(W1, W2, Wsw);

    const int gemm_grid = (NN + 63) / 64;          // 782
    const int node_grid = (NN * 32 + 255) / 256;   // 6250

    // layer 1: Hs1 = dinv*(x @ W1) ; A2 = relu(dinv*(self+nbrs) + b1)
    k_gemm_mfma<false><<<gemm_grid, 256, 0, stream>>>(x, Wsw, dinv, bufA);
    k_gather_bf<true><<<node_grid, 256, 0, stream>>>(offs, csr, dinv, b1, bufA, bufB);

    // layer 2: Hs2 = dinv*(A2 @ W2) ; agg2 = dinv*(self+nbrs)
    k_gemm_mfma<true><<<gemm_grid, 256, 0, stream>>>(bufB, Wsw + 16384, dinv, bufA);
    k_gather_bf<false><<<node_grid, 256, 0, stream>>>(offs, csr, dinv, nullptr, bufA, bufB);

    // pool (+b2) + linear head
    k_pool_logits<<<NG, 256, 0, stream>>>(bufB, b2, Wlin, blin, batch, out);
}

// Round 4
// 263.505 us; speedup vs baseline: 8.9618x; 1.4389x over previous
//
#include <hip/hip_runtime.h>

#define NN 50000     // nodes
#define NE 600000    // directed edges (self loops handled separately)
#define NG 64        // graphs
#define DIM 128      // feature dim (D == H == 128)
#define NCLS 10
#define PS 8         // pool slices per graph

typedef unsigned short ushort;
typedef __attribute__((ext_vector_type(8))) short short8;   // 8 bf16 (4 VGPRs)
typedef __attribute__((ext_vector_type(4))) float float4v;  // 4 fp32 acc

__device__ __forceinline__ ushort f2bf(float f) {
    unsigned u = __float_as_uint(f);
    u += 0x7fff + ((u >> 16) & 1);          // RNE
    return (ushort)(u >> 16);
}
__device__ __forceinline__ float bf2f(ushort h) {
    return __uint_as_float((unsigned)h << 16);
}

// ---------------- degree histogram (int) ----------------
__global__ void k_deg_count(const int* __restrict__ col, int* __restrict__ cnt) {
    int e = blockIdx.x * blockDim.x + threadIdx.x;
    if (e < NE) atomicAdd(&cnt[col[e]], 1);
}

// dinv[i] = rsqrt(1 + indeg[i])   (self loop contributes 1)
__global__ void k_dinv(const int* __restrict__ cnt, float* __restrict__ dinv) {
    int i = blockIdx.x * blockDim.x + threadIdx.x;
    if (i < NN) dinv[i] = rsqrtf(1.0f + (float)cnt[i]);
}

// ---------------- parallel scan: per-block partial sums ----------------
__global__ __launch_bounds__(256) void k_part(const int* __restrict__ cnt,
                                              int* __restrict__ partials) {
    __shared__ int sm[256];
    int t = threadIdx.x, i = blockIdx.x * 256 + t;
    sm[t] = (i < NN) ? cnt[i] : 0;
    __syncthreads();
    for (int s = 128; s > 0; s >>= 1) {
        if (t < s) sm[t] += sm[t + s];
        __syncthreads();
    }
    if (t == 0) partials[blockIdx.x] = sm[0];
}

// 1-block exclusive scan of the 196 partials
__global__ __launch_bounds__(256) void k_scanp(int* partials) {
    __shared__ int sm[256];
    int t = threadIdx.x;
    int v = (t < 196) ? partials[t] : 0;
    sm[t] = v;
    __syncthreads();
    for (int off = 1; off < 256; off <<= 1) {
        int u = (t >= off) ? sm[t - off] : 0;
        __syncthreads();
        sm[t] += u;
        __syncthreads();
    }
    if (t < 196) partials[t] = sm[t] - v;   // exclusive prefix
}

// per-block exclusive scan + base -> offsets & cursor (cursor may alias cnt_in)
__global__ __launch_bounds__(256) void k_off(const int* cnt_in, const int* __restrict__ partials,
                                             int* __restrict__ offsets, int* cursor) {
    __shared__ int sm[256];
    int t = threadIdx.x, i = blockIdx.x * 256 + t;
    int v = (i < NN) ? cnt_in[i] : 0;
    sm[t] = v;
    __syncthreads();
    for (int off = 1; off < 256; off <<= 1) {
        int u = (t >= off) ? sm[t - off] : 0;
        __syncthreads();
        sm[t] += u;
        __syncthreads();
    }
    int base = partials[blockIdx.x] + sm[t] - v;
    if (i < NN) { offsets[i] = base; cursor[i] = base; }
    if (i == NN) offsets[NN] = base;        // v==0 there => total edge count
}

// ---------------- CSR fill: sources sorted by destination ----------------
__global__ void k_csr_fill(const int* __restrict__ row, const int* __restrict__ col,
                           int* __restrict__ cursor, int* __restrict__ csr) {
    int e = blockIdx.x * blockDim.x + threadIdx.x;
    if (e < NE) {
        int c = col[e];
        int p = atomicAdd(&cursor[c], 1);
        csr[p] = row[e];
    }
}

// ---------------- W -> bf16 B-fragment order ----------------
// Wsw[(nt*4+kc)*64 + lane][j] = W[kc*32 + (lane>>4)*8 + j][nt*16 + (lane&15)]
__global__ void k_wprep(const float* __restrict__ W1, const float* __restrict__ W2,
                        ushort* __restrict__ Wsw) {
    int tid = blockIdx.x * blockDim.x + threadIdx.x;   // 2*16384 threads
    int layer = tid >> 14;
    int r = tid & 16383;
    int j = r & 7;
    int lane = (r >> 3) & 63;
    int frag = r >> 9;             // nt*4+kc
    int nt = frag >> 2, kc = frag & 3;
    int k = kc * 32 + (lane >> 4) * 8 + j;
    int n = nt * 16 + (lane & 15);
    const float* W = layer ? W2 : W1;
    Wsw[tid] = f2bf(W[k * DIM + n]);
}

// ---------------- MFMA GEMM: Hs[n,c] = dinv[n] * sum_k A[n,k] W[k,c] -------
// 4 waves/block, 16 rows per wave, full 128-col strip. All 32 B-frags in regs.
template <bool IN_BF16>
__global__ __launch_bounds__(256) void k_gemm_mfma(const void* __restrict__ Ain,
                                                   const ushort* __restrict__ Wsw,
                                                   const float* __restrict__ dinv,
                                                   ushort* __restrict__ Hs) {
    const int t = threadIdx.x;
    const int wave = t >> 6, lane = t & 63;
    const int m = lane & 15, quad = lane >> 4;
    const int row0 = blockIdx.x * 64 + wave * 16;

    short8 bfrag[8][4];
#pragma unroll
    for (int nt = 0; nt < 8; ++nt)
#pragma unroll
        for (int kc = 0; kc < 4; ++kc)
            bfrag[nt][kc] = *(const short8*)(Wsw + ((nt * 4 + kc) * 64 + lane) * 8);

    float4v acc[8];
#pragma unroll
    for (int nt = 0; nt < 8; ++nt) acc[nt] = (float4v){0.f, 0.f, 0.f, 0.f};

    const int row = row0 + m;
    const int rclamp = row < NN ? row : NN - 1;

#pragma unroll
    for (int kc = 0; kc < 4; ++kc) {
        short8 a;
        if (IN_BF16) {
            a = *(const short8*)((const ushort*)Ain + (size_t)rclamp * DIM + kc * 32 + quad * 8);
        } else {
            const float* ap = (const float*)Ain + (size_t)rclamp * DIM + kc * 32 + quad * 8;
            float4 v0 = *(const float4*)ap;
            float4 v1 = *(const float4*)(ap + 4);
            union { short8 v; ushort u[8]; } tmp;
            tmp.u[0] = f2bf(v0.x); tmp.u[1] = f2bf(v0.y);
            tmp.u[2] = f2bf(v0.z); tmp.u[3] = f2bf(v0.w);
            tmp.u[4] = f2bf(v1.x); tmp.u[5] = f2bf(v1.y);
            tmp.u[6] = f2bf(v1.z); tmp.u[7] = f2bf(v1.w);
            a = tmp.v;
        }
#pragma unroll
        for (int nt = 0; nt < 8; ++nt)
            acc[nt] = __builtin_amdgcn_mfma_f32_16x16x32_bf16(a, bfrag[nt][kc], acc[nt], 0, 0, 0);
    }

    // C/D: col = nt*16 + (lane&15), row = row0 + quad*4 + reg
#pragma unroll
    for (int reg = 0; reg < 4; ++reg) {
        int r = row0 + quad * 4 + reg;
        if (r < NN) {
            float d = dinv[r];
#pragma unroll
            for (int nt = 0; nt < 8; ++nt)
                Hs[(size_t)r * DIM + nt * 16 + m] = f2bf(d * acc[nt][reg]);
        }
    }
}

// ---------------- CSR gather (bf16): out = dinv[c]*(Hs[c] + sum Hs[r]) -----
// RELU: out = relu(out + b1) (feeds next GEMM). 32 lanes per node, 4 cols/lane.
template <bool RELU>
__global__ __launch_bounds__(256) void k_gather_bf(const int* __restrict__ offsets,
                                                   const int* __restrict__ csr,
                                                   const float* __restrict__ dinv,
                                                   const float* __restrict__ bias,
                                                   const ushort* __restrict__ Hs,
                                                   ushort* __restrict__ out) {
    int gt = blockIdx.x * blockDim.x + threadIdx.x;
    int node = gt >> 5, lane = gt & 31;
    if (node >= NN) return;
    int beg = offsets[node], end = offsets[node + 1];

    uint2 sv = *(const uint2*)(Hs + (size_t)node * DIM + lane * 4);
    float a0 = __uint_as_float(sv.x << 16);
    float a1 = __uint_as_float(sv.x & 0xffff0000u);
    float a2 = __uint_as_float(sv.y << 16);
    float a3 = __uint_as_float(sv.y & 0xffff0000u);

    int e = beg;
    for (; e + 4 <= end; e += 4) {               // 4 independent loads in flight
        int r0 = csr[e], r1 = csr[e + 1], r2 = csr[e + 2], r3 = csr[e + 3];
        uint2 v0 = *(const uint2*)(Hs + (size_t)r0 * DIM + lane * 4);
        uint2 v1 = *(const uint2*)(Hs + (size_t)r1 * DIM + lane * 4);
        uint2 v2 = *(const uint2*)(Hs + (size_t)r2 * DIM + lane * 4);
        uint2 v3 = *(const uint2*)(Hs + (size_t)r3 * DIM + lane * 4);
        a0 += __uint_as_float(v0.x << 16) + __uint_as_float(v1.x << 16)
            + __uint_as_float(v2.x << 16) + __uint_as_float(v3.x << 16);
        a1 += __uint_as_float(v0.x & 0xffff0000u) + __uint_as_float(v1.x & 0xffff0000u)
            + __uint_as_float(v2.x & 0xffff0000u) + __uint_as_float(v3.x & 0xffff0000u);
        a2 += __uint_as_float(v0.y << 16) + __uint_as_float(v1.y << 16)
            + __uint_as_float(v2.y << 16) + __uint_as_float(v3.y << 16);
        a3 += __uint_as_float(v0.y & 0xffff0000u) + __uint_as_float(v1.y & 0xffff0000u)
            + __uint_as_float(v2.y & 0xffff0000u) + __uint_as_float(v3.y & 0xffff0000u);
    }
    for (; e < end; ++e) {
        int r = csr[e];
        uint2 v = *(const uint2*)(Hs + (size_t)r * DIM + lane * 4);
        a0 += __uint_as_float(v.x << 16);
        a1 += __uint_as_float(v.x & 0xffff0000u);
        a2 += __uint_as_float(v.y << 16);
        a3 += __uint_as_float(v.y & 0xffff0000u);
    }
    float d = dinv[node];
    a0 *= d; a1 *= d; a2 *= d; a3 *= d;
    if (RELU) {
        float4 b = *(const float4*)(bias + lane * 4);
        a0 = fmaxf(a0 + b.x, 0.f);
        a1 = fmaxf(a1 + b.y, 0.f);
        a2 = fmaxf(a2 + b.z, 0.f);
        a3 = fmaxf(a3 + b.w, 0.f);
    }
    uint2 o;
    o.x = (unsigned)f2bf(a0) | ((unsigned)f2bf(a1) << 16);
    o.y = (unsigned)f2bf(a2) | ((unsigned)f2bf(a3) << 16);
    *(uint2*)(out + (size_t)node * DIM + lane * 4) = o;
}

// ---------------- pool stage 1: per-(graph,slice) partial sums -------------
__global__ __launch_bounds__(256) void k_pool_part(const ushort* __restrict__ Hf,
                                                   const int* __restrict__ batch,
                                                   float* __restrict__ partial) {
    const int g = blockIdx.x / PS, s = blockIdx.x % PS;
    const int t = threadIdx.x;
    int start;
    { int a = 0, b = NN; while (a < b) { int m = (a + b) >> 1; if (batch[m] < g) a = m + 1; else b = m; } start = a; }
    int end;
    { int a = 0, b = NN; while (a < b) { int m = (a + b) >> 1; if (batch[m] < g + 1) a = m + 1; else b = m; } end = a; }
    const int cnt = end - start;
    const int chunk = (cnt + PS - 1) / PS;
    const int lo = start + s * chunk;
    const int hi = min(lo + chunk, end);

    const int lane = t & 31, grp = t >> 5;   // 8 row-groups
    float a0 = 0.f, a1 = 0.f, a2 = 0.f, a3 = 0.f;
    for (int i = lo + grp; i < hi; i += 8) {
        uint2 v = *(const uint2*)(Hf + (size_t)i * DIM + lane * 4);
        a0 += __uint_as_float(v.x << 16);
        a1 += __uint_as_float(v.x & 0xffff0000u);
        a2 += __uint_as_float(v.y << 16);
        a3 += __uint_as_float(v.y & 0xffff0000u);
    }
    __shared__ float sm[8][DIM];
    *(float4*)&sm[grp][lane * 4] = make_float4(a0, a1, a2, a3);
    __syncthreads();
    if (t < DIM) {
        float sum = 0.f;
#pragma unroll
        for (int r = 0; r < 8; ++r) sum += sm[r][t];
        partial[(size_t)blockIdx.x * DIM + t] = sum;
    }
}

// ---------------- pool stage 2: reduce slices, + b2, linear head -----------
__global__ __launch_bounds__(128) void k_logits(const float* __restrict__ partial,
                                                const float* __restrict__ b2,
                                                const float* __restrict__ Wlin,
                                                const float* __restrict__ blin,
                                                const int* __restrict__ batch,
                                                float* __restrict__ out) {
    const int g = blockIdx.x;
    const int t = threadIdx.x;
    int start;
    { int a = 0, b = NN; while (a < b) { int m = (a + b) >> 1; if (batch[m] < g) a = m + 1; else b = m; } start = a; }
    int end;
    { int a = 0, b = NN; while (a < b) { int m = (a + b) >> 1; if (batch[m] < g + 1) a = m + 1; else b = m; } end = a; }
    const int cnt = end - start;

    __shared__ float pooled[DIM];
    float sum = 0.f;
#pragma unroll
    for (int s = 0; s < PS; ++s) sum += partial[(size_t)(g * PS + s) * DIM + t];
    pooled[t] = (cnt > 0) ? (sum / (float)cnt + b2[t]) : 0.f;
    __syncthreads();
    if (t < NCLS) {
        float s = blin[t];
        for (int k = 0; k < DIM; ++k) s += pooled[k] * Wlin[k * NCLS + t];
        out[g * NCLS + t] = s;
    }
}

extern "C" void kernel_launch(void* const* d_in, const int* in_sizes, int n_in,
                              void* d_out, int out_size, void* d_ws, size_t ws_size,
                              hipStream_t stream) {
    const float* x    = (const float*)d_in[0];
    const float* W1   = (const float*)d_in[1];
    const float* b1   = (const float*)d_in[2];
    const float* W2   = (const float*)d_in[3];
    const float* b2   = (const float*)d_in[4];
    const float* Wlin = (const float*)d_in[5];
    const float* blin = (const float*)d_in[6];
    const int* eidx   = (const int*)d_in[7];   // [2, E] flat: rows then cols
    const int* batch  = (const int*)d_in[8];
    float* out = (float*)d_out;

    char* ws = (char*)d_ws;
    float*  dinv     = (float*)(ws + 0);                   // 200000 B
    int*    cnt      = (int*)(ws + 200000);                // 200000 B (becomes cursor)
    int*    offs     = (int*)(ws + 400000);                // 200016 B (NN+1)
    int*    csr      = (int*)(ws + 600016);                // 2400000 B
    int*    partials = (int*)(ws + 3000016);               // 1024 B
    ushort* Wsw      = (ushort*)(ws + 3001040);            // 65536 B (2 layers)
    ushort* bufA     = (ushort*)(ws + 3066576);            // 12.8 MB bf16 [NN][128]
    ushort* bufB     = (ushort*)(ws + 3066576 + (size_t)NN * DIM * 2);
    // pool partials alias the CSR region (csr is dead after the last gather)
    float*  poolpt   = (float*)(ws + 600016);              // NG*PS*DIM floats = 256 KB

    const int* erow = eidx;
    const int* ecol = eidx + NE;

    // ---- CSR build + norms ----
    hipMemsetAsync(cnt, 0, (size_t)NN * 4, stream);
    k_deg_count<<<(NE + 255) / 256, 256, 0, stream>>>(ecol, cnt);
    k_dinv<<<(NN + 255) / 256, 256, 0, stream>>>(cnt, dinv);
    const int SB = (NN + 255) / 256;   // 196
    k_part<<<SB, 256, 0, stream>>>(cnt, partials);
    k_scanp<<<1, 256, 0, stream>>>(partials);
    k_off<<<SB, 256, 0, stream>>>(cnt, partials, offs, cnt /*cursor*/);
    k_csr_fill<<<(NE + 255) / 256, 256, 0, stream>>>(erow, ecol, cnt, csr);

    // ---- weights -> bf16 fragment order ----
    k_wprep<<<128, 256, 0, stream>>>(W1, W2, Wsw);

    const int gemm_grid = (NN + 63) / 64;          // 782
    const int node_grid = (NN * 32 + 255) / 256;   // 6250

    // layer 1: Hs1 = dinv*(x @ W1) ; A2 = relu(dinv*(self+nbrs) + b1)
    k_gemm_mfma<false><<<gemm_grid, 256, 0, stream>>>(x, Wsw, dinv, bufA);
    k_gather_bf<true><<<node_grid, 256, 0, stream>>>(offs, csr, dinv, b1, bufA, bufB);

    // layer 2: Hs2 = dinv*(A2 @ W2) ; agg2 = dinv*(self+nbrs)
    k_gemm_mfma<true><<<gemm_grid, 256, 0, stream>>>(bufB, Wsw + 16384, dinv, bufA);
    k_gather_bf<false><<<node_grid, 256, 0, stream>>>(offs, csr, dinv, nullptr, bufA, bufB);

    // two-stage pool (+b2) + linear head
    k_pool_part<<<NG * PS, 256, 0, stream>>>(bufB, batch, poolpt);
    k_logits<<<NG, 128, 0, stream>>>(poolpt, b2, Wlin, blin, batch, out);
}

// Round 5
// 253.808 us; speedup vs baseline: 9.3042x; 1.0382x over previous
//
#include <hip/hip_runtime.h>

#define NN 50000     // nodes
#define NE 600000    // directed edges (self loops handled separately)
#define NG 64        // graphs
#define DIM 128      // feature dim (D == H == 128)
#define NCLS 10
#define PS 8         // pool slices per graph
#define SB 196       // scan blocks = ceil(NN/256)

typedef unsigned short ushort;
typedef __attribute__((ext_vector_type(8))) short short8;   // 8 bf16 (4 VGPRs)
typedef __attribute__((ext_vector_type(4))) float float4v;  // 4 fp32 acc

__device__ __forceinline__ ushort f2bf(float f) {
    unsigned u = __float_as_uint(f);
    u += 0x7fff + ((u >> 16) & 1);          // RNE
    return (ushort)(u >> 16);
}
__device__ __forceinline__ float bf2f(ushort h) {
    return __uint_as_float((unsigned)h << 16);
}
__device__ __forceinline__ void acc8(float* a, uint4 v) {
    a[0] += __uint_as_float(v.x << 16); a[1] += __uint_as_float(v.x & 0xffff0000u);
    a[2] += __uint_as_float(v.y << 16); a[3] += __uint_as_float(v.y & 0xffff0000u);
    a[4] += __uint_as_float(v.z << 16); a[5] += __uint_as_float(v.z & 0xffff0000u);
    a[6] += __uint_as_float(v.w << 16); a[7] += __uint_as_float(v.w & 0xffff0000u);
}

// ---------------- init: zero cnt (blocks 0..SB-1) + W->bf16 frag order -----
// Wsw[(nt*4+kc)*64 + lane][j] = W[kc*32 + (lane>>4)*8 + j][nt*16 + (lane&15)]
__global__ void k_init(int* __restrict__ cnt, const float* __restrict__ W1,
                       const float* __restrict__ W2, ushort* __restrict__ Wsw) {
    int b = blockIdx.x, t = threadIdx.x;
    if (b < SB) {
        int i = b * 256 + t;
        if (i < NN) cnt[i] = 0;
    } else {
        int tid = (b - SB) * 256 + t;     // 128 blocks -> 32768 threads
        int layer = tid >> 14;
        int r = tid & 16383;
        int j = r & 7;
        int lane = (r >> 3) & 63;
        int frag = r >> 9;                // nt*4+kc
        int nt = frag >> 2, kc = frag & 3;
        int k = kc * 32 + (lane >> 4) * 8 + j;
        int n = nt * 16 + (lane & 15);
        const float* W = layer ? W2 : W1;
        Wsw[tid] = f2bf(W[k * DIM + n]);
    }
}

// ---------------- degree histogram (2 edges/thread) ----------------
__global__ void k_deg_count(const int* __restrict__ col, int* __restrict__ cnt) {
    int e = (blockIdx.x * blockDim.x + threadIdx.x) * 2;
    if (e < NE) {
        int2 c = *(const int2*)(col + e);
        atomicAdd(&cnt[c.x], 1);
        atomicAdd(&cnt[c.y], 1);
    }
}

// ---------------- per-block partial sums + dinv ----------------
__global__ __launch_bounds__(256) void k_part(const int* __restrict__ cnt,
                                              int* __restrict__ partials,
                                              float* __restrict__ dinv) {
    __shared__ int sm[256];
    int t = threadIdx.x, i = blockIdx.x * 256 + t;
    int c = (i < NN) ? cnt[i] : 0;
    if (i < NN) dinv[i] = rsqrtf(1.0f + (float)c);   // self loop contributes 1
    sm[t] = c;
    __syncthreads();
    for (int s = 128; s > 0; s >>= 1) {
        if (t < s) sm[t] += sm[t + s];
        __syncthreads();
    }
    if (t == 0) partials[blockIdx.x] = sm[0];
}

// 1-block exclusive scan of the SB partials
__global__ __launch_bounds__(256) void k_scanp(int* partials) {
    __shared__ int sm[256];
    int t = threadIdx.x;
    int v = (t < SB) ? partials[t] : 0;
    sm[t] = v;
    __syncthreads();
    for (int off = 1; off < 256; off <<= 1) {
        int u = (t >= off) ? sm[t - off] : 0;
        __syncthreads();
        sm[t] += u;
        __syncthreads();
    }
    if (t < SB) partials[t] = sm[t] - v;   // exclusive prefix
}

// per-block exclusive scan + base -> offsets & cursor (cursor may alias cnt_in)
__global__ __launch_bounds__(256) void k_off(const int* cnt_in, const int* __restrict__ partials,
                                             int* __restrict__ offsets, int* cursor) {
    __shared__ int sm[256];
    int t = threadIdx.x, i = blockIdx.x * 256 + t;
    int v = (i < NN) ? cnt_in[i] : 0;
    sm[t] = v;
    __syncthreads();
    for (int off = 1; off < 256; off <<= 1) {
        int u = (t >= off) ? sm[t - off] : 0;
        __syncthreads();
        sm[t] += u;
        __syncthreads();
    }
    int base = partials[blockIdx.x] + sm[t] - v;
    if (i < NN) { offsets[i] = base; cursor[i] = base; }
    if (i == NN) offsets[NN] = base;
}

// ---------------- CSR fill (2 edges/thread) ----------------
__global__ void k_csr_fill(const int* __restrict__ row, const int* __restrict__ col,
                           int* __restrict__ cursor, int* __restrict__ csr) {
    int e = (blockIdx.x * blockDim.x + threadIdx.x) * 2;
    if (e < NE) {
        int2 r = *(const int2*)(row + e);
        int2 c = *(const int2*)(col + e);
        int p0 = atomicAdd(&cursor[c.x], 1); csr[p0] = r.x;
        int p1 = atomicAdd(&cursor[c.y], 1); csr[p1] = r.y;
    }
}

// ---------------- MFMA GEMM: Hs[n,c] = dinv[n] * sum_k A[n,k] W[k,c] -------
template <bool IN_BF16>
__global__ __launch_bounds__(256) void k_gemm_mfma(const void* __restrict__ Ain,
                                                   const ushort* __restrict__ Wsw,
                                                   const float* __restrict__ dinv,
                                                   ushort* __restrict__ Hs) {
    const int t = threadIdx.x;
    const int wave = t >> 6, lane = t & 63;
    const int m = lane & 15, quad = lane >> 4;
    const int row0 = blockIdx.x * 64 + wave * 16;

    short8 bfrag[8][4];
#pragma unroll
    for (int nt = 0; nt < 8; ++nt)
#pragma unroll
        for (int kc = 0; kc < 4; ++kc)
            bfrag[nt][kc] = *(const short8*)(Wsw + ((nt * 4 + kc) * 64 + lane) * 8);

    float4v acc[8];
#pragma unroll
    for (int nt = 0; nt < 8; ++nt) acc[nt] = (float4v){0.f, 0.f, 0.f, 0.f};

    const int row = row0 + m;
    const int rclamp = row < NN ? row : NN - 1;

#pragma unroll
    for (int kc = 0; kc < 4; ++kc) {
        short8 a;
        if (IN_BF16) {
            a = *(const short8*)((const ushort*)Ain + (size_t)rclamp * DIM + kc * 32 + quad * 8);
        } else {
            const float* ap = (const float*)Ain + (size_t)rclamp * DIM + kc * 32 + quad * 8;
            float4 v0 = *(const float4*)ap;
            float4 v1 = *(const float4*)(ap + 4);
            union { short8 v; ushort u[8]; } tmp;
            tmp.u[0] = f2bf(v0.x); tmp.u[1] = f2bf(v0.y);
            tmp.u[2] = f2bf(v0.z); tmp.u[3] = f2bf(v0.w);
            tmp.u[4] = f2bf(v1.x); tmp.u[5] = f2bf(v1.y);
            tmp.u[6] = f2bf(v1.z); tmp.u[7] = f2bf(v1.w);
            a = tmp.v;
        }
#pragma unroll
        for (int nt = 0; nt < 8; ++nt)
            acc[nt] = __builtin_amdgcn_mfma_f32_16x16x32_bf16(a, bfrag[nt][kc], acc[nt], 0, 0, 0);
    }

    // C/D: col = nt*16 + (lane&15), row = row0 + quad*4 + reg
#pragma unroll
    for (int reg = 0; reg < 4; ++reg) {
        int r = row0 + quad * 4 + reg;
        if (r < NN) {
            float d = dinv[r];
#pragma unroll
            for (int nt = 0; nt < 8; ++nt)
                Hs[(size_t)r * DIM + nt * 16 + m] = f2bf(d * acc[nt][reg]);
        }
    }
}

// ---------------- CSR gather (bf16): out = dinv[c]*(Hs[c] + sum Hs[r]) -----
// 16 lanes/node, uint4 (8 bf16) per lane, 4 edge-rows in flight.
template <bool RELU>
__global__ __launch_bounds__(256) void k_gather_bf(const int* __restrict__ offsets,
                                                   const int* __restrict__ csr,
                                                   const float* __restrict__ dinv,
                                                   const float* __restrict__ bias,
                                                   const ushort* __restrict__ Hs,
                                                   ushort* __restrict__ out) {
    int gt = blockIdx.x * blockDim.x + threadIdx.x;
    int node = gt >> 4, lane = gt & 15;
    if (node >= NN) return;
    int beg = offsets[node], end = offsets[node + 1];
    const size_t off = (size_t)lane * 8;

    float a[8] = {0.f, 0.f, 0.f, 0.f, 0.f, 0.f, 0.f, 0.f};
    acc8(a, *(const uint4*)(Hs + (size_t)node * DIM + off));   // self loop

    int e = beg;
    for (; e + 4 <= end; e += 4) {
        int r0 = csr[e], r1 = csr[e + 1], r2 = csr[e + 2], r3 = csr[e + 3];
        uint4 v0 = *(const uint4*)(Hs + (size_t)r0 * DIM + off);
        uint4 v1 = *(const uint4*)(Hs + (size_t)r1 * DIM + off);
        uint4 v2 = *(const uint4*)(Hs + (size_t)r2 * DIM + off);
        uint4 v3 = *(const uint4*)(Hs + (size_t)r3 * DIM + off);
        acc8(a, v0); acc8(a, v1); acc8(a, v2); acc8(a, v3);
    }
    for (; e < end; ++e) {
        int r = csr[e];
        acc8(a, *(const uint4*)(Hs + (size_t)r * DIM + off));
    }

    float d = dinv[node];
#pragma unroll
    for (int j = 0; j < 8; ++j) a[j] *= d;
    if (RELU) {
        float4 b0 = *(const float4*)(bias + off);
        float4 b1 = *(const float4*)(bias + off + 4);
        a[0] = fmaxf(a[0] + b0.x, 0.f); a[1] = fmaxf(a[1] + b0.y, 0.f);
        a[2] = fmaxf(a[2] + b0.z, 0.f); a[3] = fmaxf(a[3] + b0.w, 0.f);
        a[4] = fmaxf(a[4] + b1.x, 0.f); a[5] = fmaxf(a[5] + b1.y, 0.f);
        a[6] = fmaxf(a[6] + b1.z, 0.f); a[7] = fmaxf(a[7] + b1.w, 0.f);
    }
    uint4 o;
    o.x = (unsigned)f2bf(a[0]) | ((unsigned)f2bf(a[1]) << 16);
    o.y = (unsigned)f2bf(a[2]) | ((unsigned)f2bf(a[3]) << 16);
    o.z = (unsigned)f2bf(a[4]) | ((unsigned)f2bf(a[5]) << 16);
    o.w = (unsigned)f2bf(a[6]) | ((unsigned)f2bf(a[7]) << 16);
    *(uint4*)(out + (size_t)node * DIM + off) = o;
}

// ---------------- pool stage 1: per-(graph,slice) partial sums -------------
__global__ __launch_bounds__(256) void k_pool_part(const ushort* __restrict__ Hf,
                                                   const int* __restrict__ batch,
                                                   float* __restrict__ partial) {
    const int g = blockIdx.x / PS, s = blockIdx.x % PS;
    const int t = threadIdx.x;
    int start;
    { int a = 0, b = NN; while (a < b) { int m = (a + b) >> 1; if (batch[m] < g) a = m + 1; else b = m; } start = a; }
    int end;
    { int a = 0, b = NN; while (a < b) { int m = (a + b) >> 1; if (batch[m] < g + 1) a = m + 1; else b = m; } end = a; }
    const int cnt = end - start;
    const int chunk = (cnt + PS - 1) / PS;
    const int lo = start + s * chunk;
    const int hi = min(lo + chunk, end);

    const int lane = t & 15, grp = t >> 4;   // 16 row-groups
    float a[8] = {0.f, 0.f, 0.f, 0.f, 0.f, 0.f, 0.f, 0.f};
    for (int i = lo + grp; i < hi; i += 16)
        acc8(a, *(const uint4*)(Hf + (size_t)i * DIM + lane * 8));

    __shared__ float sm[16][DIM];
    *(float4*)&sm[grp][lane * 8] = make_float4(a[0], a[1], a[2], a[3]);
    *(float4*)&sm[grp][lane * 8 + 4] = make_float4(a[4], a[5], a[6], a[7]);
    __syncthreads();
    if (t < DIM) {
        float sum = 0.f;
#pragma unroll
        for (int r = 0; r < 16; ++r) sum += sm[r][t];
        partial[(size_t)blockIdx.x * DIM + t] = sum;
    }
}

// ---------------- pool stage 2: reduce slices, + b2, linear head -----------
__global__ __launch_bounds__(128) void k_logits(const float* __restrict__ partial,
                                                const float* __restrict__ b2,
                                                const float* __restrict__ Wlin,
                                                const float* __restrict__ blin,
                                                const int* __restrict__ batch,
                                                float* __restrict__ out) {
    const int g = blockIdx.x;
    const int t = threadIdx.x;
    int start;
    { int a = 0, b = NN; while (a < b) { int m = (a + b) >> 1; if (batch[m] < g) a = m + 1; else b = m; } start = a; }
    int end;
    { int a = 0, b = NN; while (a < b) { int m = (a + b) >> 1; if (batch[m] < g + 1) a = m + 1; else b = m; } end = a; }
    const int cnt = end - start;

    __shared__ float pooled[DIM];
    float sum = 0.f;
#pragma unroll
    for (int s = 0; s < PS; ++s) sum += partial[(size_t)(g * PS + s) * DIM + t];
    pooled[t] = (cnt > 0) ? (sum / (float)cnt + b2[t]) : 0.f;
    __syncthreads();
    if (t < NCLS) {
        float s = blin[t];
        for (int k = 0; k < DIM; ++k) s += pooled[k] * Wlin[k * NCLS + t];
        out[g * NCLS + t] = s;
    }
}

extern "C" void kernel_launch(void* const* d_in, const int* in_sizes, int n_in,
                              void* d_out, int out_size, void* d_ws, size_t ws_size,
                              hipStream_t stream) {
    const float* x    = (const float*)d_in[0];
    const float* W1   = (const float*)d_in[1];
    const float* b1   = (const float*)d_in[2];
    const float* W2   = (const float*)d_in[3];
    const float* b2   = (const float*)d_in[4];
    const float* Wlin = (const float*)d_in[5];
    const float* blin = (const float*)d_in[6];
    const int* eidx   = (const int*)d_in[7];   // [2, E] flat: rows then cols
    const int* batch  = (const int*)d_in[8];
    float* out = (float*)d_out;

    char* ws = (char*)d_ws;
    float*  dinv     = (float*)(ws + 0);                   // 200000 B
    int*    cnt      = (int*)(ws + 200000);                // 200000 B (becomes cursor)
    int*    offs     = (int*)(ws + 400000);                // 200016 B (NN+1)
    int*    csr      = (int*)(ws + 600016);                // 2400000 B
    int*    partials = (int*)(ws + 3000016);               // 1024 B
    ushort* Wsw      = (ushort*)(ws + 3001040);            // 65536 B (2 layers)
    ushort* bufA     = (ushort*)(ws + 3066576);            // 12.8 MB bf16 [NN][128]
    ushort* bufB     = (ushort*)(ws + 3066576 + (size_t)NN * DIM * 2);
    // pool partials alias the CSR region (csr is dead after the last gather)
    float*  poolpt   = (float*)(ws + 600016);              // NG*PS*DIM floats = 256 KB

    const int* erow = eidx;
    const int* ecol = eidx + NE;

    // ---- CSR build + norms + weight prep ----
    k_init<<<SB + 128, 256, 0, stream>>>(cnt, W1, W2, Wsw);
    k_deg_count<<<(NE / 2 + 255) / 256, 256, 0, stream>>>(ecol, cnt);
    k_part<<<SB, 256, 0, stream>>>(cnt, partials, dinv);
    k_scanp<<<1, 256, 0, stream>>>(partials);
    k_off<<<SB, 256, 0, stream>>>(cnt, partials, offs, cnt /*cursor*/);
    k_csr_fill<<<(NE / 2 + 255) / 256, 256, 0, stream>>>(erow, ecol, cnt, csr);

    const int gemm_grid = (NN + 63) / 64;            // 782
    const int node_grid = (NN * 16 + 255) / 256;     // 3125

    // layer 1: Hs1 = dinv*(x @ W1) ; A2 = relu(dinv*(self+nbrs) + b1)
    k_gemm_mfma<false><<<gemm_grid, 256, 0, stream>>>(x, Wsw, dinv, bufA);
    k_gather_bf<true><<<node_grid, 256, 0, stream>>>(offs, csr, dinv, b1, bufA, bufB);

    // layer 2: Hs2 = dinv*(A2 @ W2) ; agg2 = dinv*(self+nbrs)
    k_gemm_mfma<true><<<gemm_grid, 256, 0, stream>>>(bufB, Wsw + 16384, dinv, bufA);
    k_gather_bf<false><<<node_grid, 256, 0, stream>>>(offs, csr, dinv, nullptr, bufA, bufB);

    // two-stage pool (+b2) + linear head
    k_pool_part<<<NG * PS, 256, 0, stream>>>(bufB, batch, poolpt);
    k_logits<<<NG, 128, 0, stream>>>(poolpt, b2, Wlin, blin, batch, out);
}

// Round 6
// 250.426 us; speedup vs baseline: 9.4299x; 1.0135x over previous
//
#include <hip/hip_runtime.h>

#define NN 50000     // nodes
#define NE 600000    // directed edges (self loops handled separately)
#define NG 64        // graphs
#define DIM 128      // feature dim (D == H == 128)
#define NCLS 10
#define PS2 16       // pool-edge slices per graph
#define SB 196       // scan blocks = ceil(NN/256)

typedef unsigned short ushort;
typedef __attribute__((ext_vector_type(8))) short short8;   // 8 bf16 (4 VGPRs)
typedef __attribute__((ext_vector_type(4))) float float4v;  // 4 fp32 acc

__device__ __forceinline__ ushort f2bf(float f) {
    unsigned u = __float_as_uint(f);
    u += 0x7fff + ((u >> 16) & 1);          // RNE
    return (ushort)(u >> 16);
}
__device__ __forceinline__ float bf2f(ushort h) {
    return __uint_as_float((unsigned)h << 16);
}
__device__ __forceinline__ void acc8(float* a, uint4 v) {
    a[0] += __uint_as_float(v.x << 16); a[1] += __uint_as_float(v.x & 0xffff0000u);
    a[2] += __uint_as_float(v.y << 16); a[3] += __uint_as_float(v.y & 0xffff0000u);
    a[4] += __uint_as_float(v.z << 16); a[5] += __uint_as_float(v.z & 0xffff0000u);
    a[6] += __uint_as_float(v.w << 16); a[7] += __uint_as_float(v.w & 0xffff0000u);
}
__device__ __forceinline__ void acc8w(float* a, uint4 v, float w) {
    a[0] = fmaf(w, __uint_as_float(v.x << 16), a[0]);
    a[1] = fmaf(w, __uint_as_float(v.x & 0xffff0000u), a[1]);
    a[2] = fmaf(w, __uint_as_float(v.y << 16), a[2]);
    a[3] = fmaf(w, __uint_as_float(v.y & 0xffff0000u), a[3]);
    a[4] = fmaf(w, __uint_as_float(v.z << 16), a[4]);
    a[5] = fmaf(w, __uint_as_float(v.z & 0xffff0000u), a[5]);
    a[6] = fmaf(w, __uint_as_float(v.w << 16), a[6]);
    a[7] = fmaf(w, __uint_as_float(v.w & 0xffff0000u), a[7]);
}

// ---------------- init: zero cnt (blocks 0..SB-1) + W->bf16 frag order -----
// Wsw[(nt*4+kc)*64 + lane][j] = W[kc*32 + (lane>>4)*8 + j][nt*16 + (lane&15)]
__global__ void k_init(int* __restrict__ cnt, const float* __restrict__ W1,
                       const float* __restrict__ W2, ushort* __restrict__ Wsw) {
    int b = blockIdx.x, t = threadIdx.x;
    if (b < SB) {
        int i = b * 256 + t;
        if (i < NN) cnt[i] = 0;
    } else {
        int tid = (b - SB) * 256 + t;     // 128 blocks -> 32768 threads
        int layer = tid >> 14;
        int r = tid & 16383;
        int j = r & 7;
        int lane = (r >> 3) & 63;
        int frag = r >> 9;                // nt*4+kc
        int nt = frag >> 2, kc = frag & 3;
        int k = kc * 32 + (lane >> 4) * 8 + j;
        int n = nt * 16 + (lane & 15);
        const float* W = layer ? W2 : W1;
        Wsw[tid] = f2bf(W[k * DIM + n]);
    }
}

// ---------------- degree histogram (2 edges/thread) ----------------
__global__ void k_deg_count(const int* __restrict__ col, int* __restrict__ cnt) {
    int e = (blockIdx.x * blockDim.x + threadIdx.x) * 2;
    if (e < NE) {
        int2 c = *(const int2*)(col + e);
        atomicAdd(&cnt[c.x], 1);
        atomicAdd(&cnt[c.y], 1);
    }
}

// ---------------- per-block partial sums + dinv ----------------
__global__ __launch_bounds__(256) void k_part(const int* __restrict__ cnt,
                                              int* __restrict__ partials,
                                              float* __restrict__ dinv) {
    __shared__ int sm[256];
    int t = threadIdx.x, i = blockIdx.x * 256 + t;
    int c = (i < NN) ? cnt[i] : 0;
    if (i < NN) dinv[i] = rsqrtf(1.0f + (float)c);   // self loop contributes 1
    sm[t] = c;
    __syncthreads();
    for (int s = 128; s > 0; s >>= 1) {
        if (t < s) sm[t] += sm[t + s];
        __syncthreads();
    }
    if (t == 0) partials[blockIdx.x] = sm[0];
}

// 1-block exclusive scan of the SB partials
__global__ __launch_bounds__(256) void k_scanp(int* partials) {
    __shared__ int sm[256];
    int t = threadIdx.x;
    int v = (t < SB) ? partials[t] : 0;
    sm[t] = v;
    __syncthreads();
    for (int off = 1; off < 256; off <<= 1) {
        int u = (t >= off) ? sm[t - off] : 0;
        __syncthreads();
        sm[t] += u;
        __syncthreads();
    }
    if (t < SB) partials[t] = sm[t] - v;   // exclusive prefix
}

// per-block exclusive scan + base -> offsets & cursor (cursor may alias cnt_in)
__global__ __launch_bounds__(256) void k_off(const int* cnt_in, const int* __restrict__ partials,
                                             int* __restrict__ offsets, int* cursor) {
    __shared__ int sm[256];
    int t = threadIdx.x, i = blockIdx.x * 256 + t;
    int v = (i < NN) ? cnt_in[i] : 0;
    sm[t] = v;
    __syncthreads();
    for (int off = 1; off < 256; off <<= 1) {
        int u = (t >= off) ? sm[t - off] : 0;
        __syncthreads();
        sm[t] += u;
        __syncthreads();
    }
    int base = partials[blockIdx.x] + sm[t] - v;
    if (i < NN) { offsets[i] = base; cursor[i] = base; }
    if (i == NN) offsets[NN] = base;
}

// ---------------- CSR fill (2 edges/thread) + per-edge dst weight ----------
__global__ void k_csr_fill(const int* __restrict__ row, const int* __restrict__ col,
                           const float* __restrict__ dinv,
                           int* __restrict__ cursor, int* __restrict__ csr,
                           float* __restrict__ dnorm) {
    int e = (blockIdx.x * blockDim.x + threadIdx.x) * 2;
    if (e < NE) {
        int2 r = *(const int2*)(row + e);
        int2 c = *(const int2*)(col + e);
        int p0 = atomicAdd(&cursor[c.x], 1); csr[p0] = r.x; dnorm[p0] = dinv[c.x];
        int p1 = atomicAdd(&cursor[c.y], 1); csr[p1] = r.y; dnorm[p1] = dinv[c.y];
    }
}

// ---------------- MFMA GEMM: Hs[n,c] = dinv[n] * sum_k A[n,k] W[k,c] -------
template <bool IN_BF16>
__global__ __launch_bounds__(256) void k_gemm_mfma(const void* __restrict__ Ain,
                                                   const ushort* __restrict__ Wsw,
                                                   const float* __restrict__ dinv,
                                                   ushort* __restrict__ Hs) {
    const int t = threadIdx.x;
    const int wave = t >> 6, lane = t & 63;
    const int m = lane & 15, quad = lane >> 4;
    const int row0 = blockIdx.x * 64 + wave * 16;

    short8 bfrag[8][4];
#pragma unroll
    for (int nt = 0; nt < 8; ++nt)
#pragma unroll
        for (int kc = 0; kc < 4; ++kc)
            bfrag[nt][kc] = *(const short8*)(Wsw + ((nt * 4 + kc) * 64 + lane) * 8);

    float4v acc[8];
#pragma unroll
    for (int nt = 0; nt < 8; ++nt) acc[nt] = (float4v){0.f, 0.f, 0.f, 0.f};

    const int row = row0 + m;
    const int rclamp = row < NN ? row : NN - 1;

#pragma unroll
    for (int kc = 0; kc < 4; ++kc) {
        short8 a;
        if (IN_BF16) {
            a = *(const short8*)((const ushort*)Ain + (size_t)rclamp * DIM + kc * 32 + quad * 8);
        } else {
            const float* ap = (const float*)Ain + (size_t)rclamp * DIM + kc * 32 + quad * 8;
            float4 v0 = *(const float4*)ap;
            float4 v1 = *(const float4*)(ap + 4);
            union { short8 v; ushort u[8]; } tmp;
            tmp.u[0] = f2bf(v0.x); tmp.u[1] = f2bf(v0.y);
            tmp.u[2] = f2bf(v0.z); tmp.u[3] = f2bf(v0.w);
            tmp.u[4] = f2bf(v1.x); tmp.u[5] = f2bf(v1.y);
            tmp.u[6] = f2bf(v1.z); tmp.u[7] = f2bf(v1.w);
            a = tmp.v;
        }
#pragma unroll
        for (int nt = 0; nt < 8; ++nt)
            acc[nt] = __builtin_amdgcn_mfma_f32_16x16x32_bf16(a, bfrag[nt][kc], acc[nt], 0, 0, 0);
    }

    // C/D: col = nt*16 + (lane&15), row = row0 + quad*4 + reg
#pragma unroll
    for (int reg = 0; reg < 4; ++reg) {
        int r = row0 + quad * 4 + reg;
        if (r < NN) {
            float d = dinv[r];
#pragma unroll
            for (int nt = 0; nt < 8; ++nt)
                Hs[(size_t)r * DIM + nt * 16 + m] = f2bf(d * acc[nt][reg]);
        }
    }
}

// ---------------- CSR gather (bf16): out = relu(dinv[c]*(Hs[c]+sum Hs[r])+b)
// 16 lanes/node, uint4 (8 bf16) per lane, up to 8 edge-rows in flight.
__global__ __launch_bounds__(256) void k_gather_bf(const int* __restrict__ offsets,
                                                   const int* __restrict__ csr,
                                                   const float* __restrict__ dinv,
                                                   const float* __restrict__ bias,
                                                   const ushort* __restrict__ Hs,
                                                   ushort* __restrict__ out) {
    int gt = blockIdx.x * blockDim.x + threadIdx.x;
    int node = gt >> 4, lane = gt & 15;
    if (node >= NN) return;
    int beg = offsets[node], end = offsets[node + 1];
    const size_t off = (size_t)lane * 8;

    float a[8] = {0.f, 0.f, 0.f, 0.f, 0.f, 0.f, 0.f, 0.f};
    acc8(a, *(const uint4*)(Hs + (size_t)node * DIM + off));   // self loop

    int e = beg;
    for (; e + 8 <= end; e += 8) {
        int r0 = csr[e], r1 = csr[e + 1], r2 = csr[e + 2], r3 = csr[e + 3];
        int r4 = csr[e + 4], r5 = csr[e + 5], r6 = csr[e + 6], r7 = csr[e + 7];
        uint4 v0 = *(const uint4*)(Hs + (size_t)r0 * DIM + off);
        uint4 v1 = *(const uint4*)(Hs + (size_t)r1 * DIM + off);
        uint4 v2 = *(const uint4*)(Hs + (size_t)r2 * DIM + off);
        uint4 v3 = *(const uint4*)(Hs + (size_t)r3 * DIM + off);
        uint4 v4 = *(const uint4*)(Hs + (size_t)r4 * DIM + off);
        uint4 v5 = *(const uint4*)(Hs + (size_t)r5 * DIM + off);
        uint4 v6 = *(const uint4*)(Hs + (size_t)r6 * DIM + off);
        uint4 v7 = *(const uint4*)(Hs + (size_t)r7 * DIM + off);
        acc8(a, v0); acc8(a, v1); acc8(a, v2); acc8(a, v3);
        acc8(a, v4); acc8(a, v5); acc8(a, v6); acc8(a, v7);
    }
    for (; e + 4 <= end; e += 4) {
        int r0 = csr[e], r1 = csr[e + 1], r2 = csr[e + 2], r3 = csr[e + 3];
        uint4 v0 = *(const uint4*)(Hs + (size_t)r0 * DIM + off);
        uint4 v1 = *(const uint4*)(Hs + (size_t)r1 * DIM + off);
        uint4 v2 = *(const uint4*)(Hs + (size_t)r2 * DIM + off);
        uint4 v3 = *(const uint4*)(Hs + (size_t)r3 * DIM + off);
        acc8(a, v0); acc8(a, v1); acc8(a, v2); acc8(a, v3);
    }
    for (; e < end; ++e) {
        int r = csr[e];
        acc8(a, *(const uint4*)(Hs + (size_t)r * DIM + off));
    }

    float d = dinv[node];
    float4 b0 = *(const float4*)(bias + off);
    float4 b1 = *(const float4*)(bias + off + 4);
    a[0] = fmaxf(fmaf(a[0], d, b0.x), 0.f); a[1] = fmaxf(fmaf(a[1], d, b0.y), 0.f);
    a[2] = fmaxf(fmaf(a[2], d, b0.z), 0.f); a[3] = fmaxf(fmaf(a[3], d, b0.w), 0.f);
    a[4] = fmaxf(fmaf(a[4], d, b1.x), 0.f); a[5] = fmaxf(fmaf(a[5], d, b1.y), 0.f);
    a[6] = fmaxf(fmaf(a[6], d, b1.z), 0.f); a[7] = fmaxf(fmaf(a[7], d, b1.w), 0.f);
    uint4 o;
    o.x = (unsigned)f2bf(a[0]) | ((unsigned)f2bf(a[1]) << 16);
    o.y = (unsigned)f2bf(a[2]) | ((unsigned)f2bf(a[3]) << 16);
    o.z = (unsigned)f2bf(a[4]) | ((unsigned)f2bf(a[5]) << 16);
    o.w = (unsigned)f2bf(a[6]) | ((unsigned)f2bf(a[7]) << 16);
    *(uint4*)(out + (size_t)node * DIM + off) = o;
}

// ---------------- fused layer-2 aggregation + pooling (edge-parallel) ------
// pooledsum[g] = sum_{n in g} dinv[n]*Hs2[n] + sum_{e: dst in g} dnorm[e]*Hs2[csr[e]]
// CSR is dst-sorted and batch sorted => per-graph edges are one contiguous range.
__global__ __launch_bounds__(256) void k_pool_edge(const int* __restrict__ offsets,
                                                   const int* __restrict__ csr,
                                                   const float* __restrict__ dnorm,
                                                   const float* __restrict__ dinv,
                                                   const int* __restrict__ batch,
                                                   const ushort* __restrict__ Hs,
                                                   float* __restrict__ partial) {
    const int g = blockIdx.x / PS2, s = blockIdx.x % PS2;
    const int t = threadIdx.x;
    int start;
    { int a = 0, b = NN; while (a < b) { int m = (a + b) >> 1; if (batch[m] < g) a = m + 1; else b = m; } start = a; }
    int end;
    { int a = 0, b = NN; while (a < b) { int m = (a + b) >> 1; if (batch[m] < g + 1) a = m + 1; else b = m; } end = a; }

    const int lane = t & 15, item = t >> 4;   // 16 lanes/row, 16 rows in flight
    const size_t off = (size_t)lane * 8;
    float a[8] = {0.f, 0.f, 0.f, 0.f, 0.f, 0.f, 0.f, 0.f};

    // edge term: slice of this graph's contiguous CSR range
    {
        const int elo = offsets[start], ehi = offsets[end];
        const int ecnt = ehi - elo;
        const int chunk = (ecnt + PS2 - 1) / PS2;
        const int lo = elo + s * chunk;
        const int hi = min(lo + chunk, ehi);
        int e = lo + item;
        for (; e + 16 < hi; e += 32) {      // 2 rows in flight per thread
            int r0 = csr[e];      float w0 = dnorm[e];
            int r1 = csr[e + 16]; float w1 = dnorm[e + 16];
            uint4 v0 = *(const uint4*)(Hs + (size_t)r0 * DIM + off);
            uint4 v1 = *(const uint4*)(Hs + (size_t)r1 * DIM + off);
            acc8w(a, v0, w0); acc8w(a, v1, w1);
        }
        for (; e < hi; e += 16) {
            int r = csr[e]; float w = dnorm[e];
            acc8w(a, *(const uint4*)(Hs + (size_t)r * DIM + off), w);
        }
    }
    // self term: slice of this graph's node range (sequential reads)
    {
        const int ncnt = end - start;
        const int chunk = (ncnt + PS2 - 1) / PS2;
        const int lo = start + s * chunk;
        const int hi = min(lo + chunk, end);
        for (int n = lo + item; n < hi; n += 16) {
            float w = dinv[n];
            acc8w(a, *(const uint4*)(Hs + (size_t)n * DIM + off), w);
        }
    }

    __shared__ float sm[16][DIM];
    *(float4*)&sm[item][lane * 8] = make_float4(a[0], a[1], a[2], a[3]);
    *(float4*)&sm[item][lane * 8 + 4] = make_float4(a[4], a[5], a[6], a[7]);
    __syncthreads();
    if (t < DIM) {
        float sum = 0.f;
#pragma unroll
        for (int r = 0; r < 16; ++r) sum += sm[r][t];
        partial[(size_t)blockIdx.x * DIM + t] = sum;
    }
}

// ---------------- reduce slices, /cnt, + b2, linear head ----------------
__global__ __launch_bounds__(128) void k_logits(const float* __restrict__ partial,
                                                const float* __restrict__ b2,
                                                const float* __restrict__ Wlin,
                                                const float* __restrict__ blin,
                                                const int* __restrict__ batch,
                                                float* __restrict__ out) {
    const int g = blockIdx.x;
    const int t = threadIdx.x;
    int start;
    { int a = 0, b = NN; while (a < b) { int m = (a + b) >> 1; if (batch[m] < g) a = m + 1; else b = m; } start = a; }
    int end;
    { int a = 0, b = NN; while (a < b) { int m = (a + b) >> 1; if (batch[m] < g + 1) a = m + 1; else b = m; } end = a; }
    const int cnt = end - start;

    __shared__ float pooled[DIM];
    float sum = 0.f;
#pragma unroll
    for (int s = 0; s < PS2; ++s) sum += partial[(size_t)(g * PS2 + s) * DIM + t];
    pooled[t] = (cnt > 0) ? (sum / (float)cnt + b2[t]) : 0.f;
    __syncthreads();
    if (t < NCLS) {
        float s = blin[t];
        for (int k = 0; k < DIM; ++k) s += pooled[k] * Wlin[k * NCLS + t];
        out[g * NCLS + t] = s;
    }
}

extern "C" void kernel_launch(void* const* d_in, const int* in_sizes, int n_in,
                              void* d_out, int out_size, void* d_ws, size_t ws_size,
                              hipStream_t stream) {
    const float* x    = (const float*)d_in[0];
    const float* W1   = (const float*)d_in[1];
    const float* b1   = (const float*)d_in[2];
    const float* W2   = (const float*)d_in[3];
    const float* b2   = (const float*)d_in[4];
    const float* Wlin = (const float*)d_in[5];
    const float* blin = (const float*)d_in[6];
    const int* eidx   = (const int*)d_in[7];   // [2, E] flat: rows then cols
    const int* batch  = (const int*)d_in[8];
    float* out = (float*)d_out;

    char* ws = (char*)d_ws;
    float*  dinv     = (float*)(ws + 0);                   // 200000 B
    int*    cnt      = (int*)(ws + 200000);                // 200000 B (becomes cursor)
    int*    offs     = (int*)(ws + 400000);                // 200016 B (NN+1)
    int*    csr      = (int*)(ws + 600016);                // 2400000 B
    float*  dnorm    = (float*)(ws + 3000016);             // 2400000 B
    int*    partials = (int*)(ws + 5400016);               // 1024 B
    ushort* Wsw      = (ushort*)(ws + 5401040);            // 65536 B (2 layers)
    ushort* bufA     = (ushort*)(ws + 5466576);            // 12.8 MB bf16 [NN][128]
    ushort* bufB     = (ushort*)(ws + 5466576 + (size_t)NN * DIM * 2);
    float*  poolpt   = (float*)(ws + 5466576 + 2 * (size_t)NN * DIM * 2);  // 512 KB

    const int* erow = eidx;
    const int* ecol = eidx + NE;

    // ---- CSR build + norms + weight prep ----
    k_init<<<SB + 128, 256, 0, stream>>>(cnt, W1, W2, Wsw);
    k_deg_count<<<(NE / 2 + 255) / 256, 256, 0, stream>>>(ecol, cnt);
    k_part<<<SB, 256, 0, stream>>>(cnt, partials, dinv);
    k_scanp<<<1, 256, 0, stream>>>(partials);
    k_off<<<SB, 256, 0, stream>>>(cnt, partials, offs, cnt /*cursor*/);
    k_csr_fill<<<(NE / 2 + 255) / 256, 256, 0, stream>>>(erow, ecol, dinv, cnt, csr, dnorm);

    const int gemm_grid = (NN + 63) / 64;            // 782
    const int node_grid = (NN * 16 + 255) / 256;     // 3125

    // layer 1: Hs1 = dinv*(x @ W1) ; A2 = relu(dinv*(self+nbrs) + b1)
    k_gemm_mfma<false><<<gemm_grid, 256, 0, stream>>>(x, Wsw, dinv, bufA);
    k_gather_bf<<<node_grid, 256, 0, stream>>>(offs, csr, dinv, b1, bufA, bufB);

    // layer 2: Hs2 = dinv*(A2 @ W2) ; fused aggregation+pool (no per-node agg2)
    k_gemm_mfma<true><<<gemm_grid, 256, 0, stream>>>(bufB, Wsw + 16384, dinv, bufA);
    k_pool_edge<<<NG * PS2, 256, 0, stream>>>(offs, csr, dnorm, dinv, batch, bufA, poolpt);

    // reduce + b2 + linear head
    k_logits<<<NG, 128, 0, stream>>>(poolpt, b2, Wlin, blin, batch, out);
}